// Round 1
// baseline (260.092 us; speedup 1.0000x reference)
//
#include <hip/hip_runtime.h>
#include <hip/hip_bf16.h>
#include <math.h>

// ---------------- problem constants ----------------
#define A_    32
#define B_    32
#define PS    16
#define KK_   9
#define KKA_  288      // KK_*A_
#define OH_   7
#define L_    49
#define NB    4
#define NSITE 196      // NB*L_
#define NCOLS 3136     // NSITE*16

#define LAM1 5.0e-4f        // 0.01*(1-0.95^1)
#define LAM2 9.75e-4f       // 0.01*(1-0.95^2)
#define LAM3 1.42625e-3f    // 0.01*(1-0.95^3)
#define LOG_LN2PI 0.6086775903077413f  // log(log(2*pi))

typedef _Float16 half2v __attribute__((ext_vector_type(2)));
typedef short    short8 __attribute__((ext_vector_type(8)));   // 8 bf16 (4 VGPRs)
typedef float    floatx4 __attribute__((ext_vector_type(4)));

static __device__ __forceinline__ float san(float x, float lo, float hi){
    return fminf(fmaxf(x, lo), hi);
}

static __device__ __forceinline__ float dot2acc(half2v a, half2v b, float c){
#if __has_builtin(__builtin_amdgcn_fdot2)
    return __builtin_amdgcn_fdot2(a, b, c, false);
#else
    return c + (float)a.x*(float)b.x + (float)a.y*(float)b.y;
#endif
}

// ================= K1: fused prep (cpr tables + full Xt unfold) =================
__global__ void k_prep(const float* __restrict__ fw, const float* __restrict__ pose,
                       ushort* __restrict__ cpr, float* __restrict__ csum,
                       __hip_bfloat16* __restrict__ Xt, int nc)
{
    if ((int)blockIdx.x < nc){
        int id = (int)blockIdx.x*256 + threadIdx.x;
        if (id >= 16*288) return;
        int p = id / 288, m = id % 288;
        float acc = fw[(0*16 + p)*2 + 0];
        for (int k = 1; k <= 143; ++k){
            float re = fw[(k*16 + p)*2 + 0];
            float im = fw[(k*16 + p)*2 + 1];
            int km = (k*m) % 288;
            float ang = 0.021816615649929116f * (float)km;  // 2*pi/288
            float s, c; __sincosf(ang, &s, &c);
            acc += 2.0f*(re*c - im*s);
        }
        float re144 = fw[(144*16 + p)*2 + 0];
        acc += re144 * ((m & 1) ? -1.0f : 1.0f);
        float cv = acc * (1.0f/288.0f);
        if (m == 0) cv += 1.0f;                            // + identity (residual)
        cv = san(cv, -1e4f, 1e4f);

        __hip_bfloat16 hb = __float2bfloat16(cv);
        float hif = __bfloat162float(hb);
        __hip_bfloat16 lb = __float2bfloat16(cv - hif);
        ushort hi = *(ushort*)&hb, lo = *(ushort*)&lb;

        ushort* c0h = cpr + p*592;
        ushort* c1h = cpr + 16*592   + p*592;
        ushort* c0l = cpr + 16*592*2 + p*592;
        ushort* c1l = cpr + 16*592*3 + p*592;
        int x1 = 288 - m;
        c0h[x1] = hi;  c0l[x1] = lo;
        c1h[x1-1] = hi; c1l[x1-1] = lo;
        if (m >= 1){
            int x2 = 576 - m;
            c0h[x2] = hi;  c0l[x2] = lo;
            c1h[x2-1] = hi; c1l[x2-1] = lo;
        } else {
            c0h[0] = hi; c0l[0] = lo;
            csum[p] = san(1.0f + fw[(0*16 + p)*2 + 0], -1e4f, 1e4f);
        }
        return;
    }
    int id = ((int)blockIdx.x - nc)*256 + threadIdx.x;
    if (id >= NCOLS*KKA_) return;
    int c = id / KKA_, j = id % KKA_;
    int n = c >> 4, q = c & 15;
    int bs = n / L_, l = n % L_, oy = l / OH_, ox = l % OH_;
    int kk = j >> 5, a = j & 31;
    int y = oy*2 - 1 + kk/3, x = ox*2 - 1 + kk%3;
    float v = 0.f;
    if ((unsigned)y < 14u && (unsigned)x < 14u)
        v = pose[((bs*(A_*PS) + a*PS + q)*14 + y)*14 + x];
    Xt[id] = __float2bfloat16(san(v, -1e4f, 1e4f));
}

// ================= K2: MEGA — per-site MFMA GEMM + v + 3 fused EM iterations =================
// Restructured for latency (196 blocks, 1/CU, 2 waves/SIMD — barriers were the cost):
//  - phase 1: double-buffered 'us' -> 1 barrier/chunk (was 2); Xt B-fragments hoisted
//    into bf[9] registers (were re-loaded from global 18x).
//  - EM iterations: batched phases. Phase A computes ALL 288 d(i) into dall[288][34]
//    (no internal barriers), phase B does all 18 softmax groups in-place, phase C does
//    all T-sums. 3 barriers/iteration instead of 36.
//  - dall (39168 B) aliases the phase-1 us double-buffer region. v split: 56 pairs in
//    LDS (114688 B) + 88 pairs in registers. Total LDS 155136 B.
__launch_bounds__(512, 1)
__global__ void
k_mega(const ushort* __restrict__ cpr, const __hip_bfloat16* __restrict__ Xt,
       const float* __restrict__ a_in,
       const float* __restrict__ mpw, const float* __restrict__ mpb,
       const float* __restrict__ csum,
       const float* __restrict__ beta_u, const float* __restrict__ beta_a,
       float* __restrict__ out)
{
    const int nl = blockIdx.x;          // site
    const int t = threadIdx.x;          // 512
    const int Bc = t >> 4, p = t & 15;  // EM thread = (Bc, p)
    const int bs = nl / L_, l = nl % L_;

    __shared__ uint v_lds[56][512];                 // 114688 B: v pairs chunks 0..6
    __shared__ __align__(16) float scratch[9792];   // 39168 B: dall[288][34] | us dbuf 2x8448B
    __shared__ float a_s[KKA_];                     // 1152 B
    __shared__ float cst[32];                       // 128 B   => 155136 B total

    float* const dall = scratch;

    // unfold this site's activation row
    for (int j = t; j < KKA_; j += 512){
        int kk = j >> 5, a = j & 31;
        int oy = l / OH_, ox = l % OH_;
        int y = oy*2 - 1 + kk/3, x = ox*2 - 1 + kk%3;
        float v = 0.f;
        if ((unsigned)y < 14u && (unsigned)x < 14u)
            v = a_in[((bs*A_ + a)*14 + y)*14 + x];
        a_s[j] = san(v, 0.f, 1e4f);
    }
    // per-thread weight row as packed fp16
    half2v w_h[8];
    #pragma unroll
    for (int k = 0; k < 8; ++k){
        w_h[k].x = (_Float16)mpw[t*16 + 2*k];
        w_h[k].y = (_Float16)mpw[t*16 + 2*k + 1];
    }
    const float vb = mpb[t] * csum[p];  // bias pushed through the filter
    const float bu = beta_u[Bc];
    const float ba = beta_a[Bc];

    // ---- GEMM lane mapping: wave w handles p_g in {2w, 2w+1} ----
    const int w = t >> 6, lane = t & 63;
    const int mn = lane & 15, quad = lane >> 4;
    const int p0 = w*2;

    // hoist chunk-invariant Xt B-fragments into registers (was 18x re-load)
    short8 bf[9];
    {
        const __hip_bfloat16* xrow = Xt + (nl*16 + mn)*KKA_ + quad*8;
        #pragma unroll
        for (int k = 0; k < 9; ++k) bf[k] = *(const short8*)&xrow[k*32];
    }
    __syncthreads();                    // a_s ready

    // S0tot: 4 accumulators to shorten the dependent-add chain
    float s0a = 0.f, s0b = 0.f, s0c = 0.f, s0d = 0.f;
    for (int j = 0; j < KKA_; j += 4){
        s0a += a_s[j]; s0b += a_s[j+1]; s0c += a_s[j+2]; s0d += a_s[j+3];
    }
    const float S0tot = (s0a + s0b) + (s0c + s0d);

    float S1 = 0.f, S2 = 0.f;
    half2v v_h[88];

    auto do_chunk = [&](int ch, _Float16* usb){
        floatx4 accA = {0,0,0,0}, accB = {0,0,0,0};
        for (int k0i = 0; k0i < 9; ++k0i){
            const int k0 = k0i*32;
            short8 bfrag = bf[k0i];
            #pragma unroll
            for (int pp = 0; pp < 2; ++pp){
                const int pg = p0 + pp;
                int o = 288 + k0 + quad*8 - (ch*16 + mn);
                int sel = o & 1, off = o - sel;
                const ushort* bh = cpr + (sel ? 16*592 : 0) + pg*592;
                const ushort* bl = cpr + 16*592*2 + (sel ? 16*592 : 0) + pg*592;
                short8 ah = *(const short8*)&bh[off];
                short8 al = *(const short8*)&bl[off];
                floatx4 acc = pp ? accB : accA;
                acc = __builtin_amdgcn_mfma_f32_16x16x32_bf16(ah, bfrag, acc, 0, 0, 0);
                acc = __builtin_amdgcn_mfma_f32_16x16x32_bf16(al, bfrag, acc, 0, 0, 0);
                if (pp) accB = acc; else accA = acc;
            }
        }
        #pragma unroll
        for (int r = 0; r < 4; ++r){
            usb[p0*264     + (quad*4 + r)*16 + mn] = (_Float16)accA[r];
            usb[(p0+1)*264 + (quad*4 + r)*16 + mn] = (_Float16)accB[r];
        }
    };

    auto vpair = [&](const _Float16* urow, int s, float& v0o, float& v1o){
        union { uint4 u4; half2v h2[4]; } A0, A1, B0, B1;
        A0.u4 = *(const uint4*)&urow[(2*s)*16];
        A1.u4 = *(const uint4*)&urow[(2*s)*16 + 8];
        B0.u4 = *(const uint4*)&urow[(2*s+1)*16];
        B1.u4 = *(const uint4*)&urow[(2*s+1)*16 + 8];
        float v0 = vb, v1 = vb;
        #pragma unroll
        for (int m = 0; m < 4; ++m){
            v0 = dot2acc(A0.h2[m], w_h[m],   v0);
            v0 = dot2acc(A1.h2[m], w_h[4+m], v0);
            v1 = dot2acc(B0.h2[m], w_h[m],   v1);
            v1 = dot2acc(B1.h2[m], w_h[4+m], v1);
        }
        v0o = v0; v1o = v1;
    };

    // ---- phase 1: 18 chunks, double-buffered us, ONE barrier per chunk ----
    // (writes of chunk ch+2 to buffer b happen after barrier(ch+1), which orders
    //  them after all reads of chunk ch from the same buffer)
    for (int ch = 0; ch < 7; ++ch){                 // v -> LDS
        _Float16* usb = ((_Float16*)scratch) + (ch & 1)*4224;
        do_chunk(ch, usb);
        __syncthreads();                            // us chunk ready
        const _Float16* urow = &usb[p*264];
        #pragma unroll
        for (int s = 0; s < 8; ++s){
            float v0, v1; vpair(urow, s, v0, v1);
            const int i0 = ch*16 + 2*s;
            const float a0 = a_s[i0], a1 = a_s[i0+1];
            S1 += a0*v0 + a1*v1;
            S2 += a0*v0*v0 + a1*v1*v1;
            union { half2v h; uint u; } cv;
            cv.h.x = (_Float16)v0; cv.h.y = (_Float16)v1;
            v_lds[ch*8 + s][t] = cv.u;
        }
    }
    #pragma unroll
    for (int c2 = 0; c2 < 11; ++c2){                // v -> regs (constant indices)
        const int ch = 7 + c2;
        _Float16* usb = ((_Float16*)scratch) + (ch & 1)*4224;
        do_chunk(ch, usb);
        __syncthreads();
        const _Float16* urow = &usb[p*264];
        #pragma unroll
        for (int s = 0; s < 8; ++s){
            float v0, v1; vpair(urow, s, v0, v1);
            const int i0 = ch*16 + 2*s;
            const float a0 = a_s[i0], a1 = a_s[i0+1];
            S1 += a0*v0 + a1*v1;
            S2 += a0*v0*v0 + a1*v1*v1;
            half2v vh; vh.x = (_Float16)v0; vh.y = (_Float16)v1;
            v_h[c2*8 + s] = vh;
        }
    }

    // iter-1 m-step (r = 1/32 exactly); mu/i2s live in registers
    float mu_r, i2s_r;
    {
        const float rs  = S0tot * (1.0f/32.0f);
        const float inv = 1.0f / (rs + 1e-12f);
        const float S1r = S1 * (1.0f/32.0f), S2r = S2 * (1.0f/32.0f);
        mu_r = S1r * inv;
        const float sg  = fmaxf((S2r - 2.f*mu_r*S1r + mu_r*mu_r*rs) * inv, 0.f) + 1e-12f;
        i2s_r = 0.5f / sg;
        const float lg  = logf(sg);
        float cs = (bu + 0.5f*lg) * rs;
        float ls = lg + LOG_LN2PI;
        #pragma unroll
        for (int m = 1; m < 16; m <<= 1){ cs += __shfl_xor(cs, m, 16); ls += __shfl_xor(ls, m, 16); }
        const float aout = san(1.f/(1.f + expf(-LAM1*(ba - cs))), 1e-30f, 1.f);
        if (p == 0) cst[Bc] = logf(aout) - 0.5f*ls;
    }
    __syncthreads();    // publish cst AND protect us-region reuse as dall

    // ---- iterations 2,3: batched phases, 3 barriers each (was 36) ----
    const int b0 = p & 1, b1 = (p>>1)&1, b2 = (p>>2)&1, b3 = (p>>3)&1;
    const int isub = t >> 5, Bce = t & 31;
    float muF = 0.f, aF = 0.f;
    for (int it = 0; it < 2; ++it){
        const float lam = it ? LAM3 : LAM2;

        // ---- phase A: all 288 d(i) -> dall[(i)*34 + Bc], no internal barriers ----
        auto dtree = [&](int ibase, auto getpair){
            float e1[8], e2[4], e3[2], dfin;
            #pragma unroll
            for (int s = 0; s < 8; ++s){
                float v0, v1; getpair(s, v0, v1);
                float d0 = v0 - mu_r, d1 = v1 - mu_r;
                float ea = d0*d0*i2s_r, eb = d1*d1*i2s_r;
                float aown  = b0 ? eb : ea;
                float asend = b0 ? ea : eb;
                e1[s] = aown + __shfl_xor(asend, 1);
            }
            #pragma unroll
            for (int s = 0; s < 4; ++s){
                float aown  = b1 ? e1[2*s+1] : e1[2*s];
                float asend = b1 ? e1[2*s]   : e1[2*s+1];
                e2[s] = aown + __shfl_xor(asend, 2);
            }
            #pragma unroll
            for (int s = 0; s < 2; ++s){
                float aown  = b2 ? e2[2*s+1] : e2[2*s];
                float asend = b2 ? e2[2*s]   : e2[2*s+1];
                e3[s] = aown + __shfl_xor(asend, 4);
            }
            {
                float aown  = b3 ? e3[1] : e3[0];
                float asend = b3 ? e3[0] : e3[1];
                dfin = aown + __shfl_xor(asend, 8);
            }
            dall[(ibase + p)*34 + Bc] = dfin;        // lane p holds d(i = ibase+p)
        };
        #pragma unroll
        for (int g = 0; g < 7; ++g)
            dtree(g*16, [&](int s, float& v0, float& v1){
                union { uint u; half2v h; } cv; cv.u = v_lds[g*8 + s][t];
                v0 = (float)cv.h.x; v1 = (float)cv.h.y; });
        #pragma unroll
        for (int c2 = 0; c2 < 11; ++c2)
            dtree((7+c2)*16, [&](int s, float& v0, float& v1){
                half2v vh = v_h[c2*8 + s];
                v0 = (float)vh.x; v1 = (float)vh.y; });
        __syncthreads();                             // (1) dall ready

        // ---- phase B: softmax over B for ALL i, in place; thread -> (isub, Bce) ----
        {
            const float cb = cst[Bce];
            #pragma unroll
            for (int g = 0; g < 18; ++g){
                float* dp = &dall[(g*16 + isub)*34 + Bce];
                float lnap = cb - *dp;
                float mx = lnap;
                #pragma unroll
                for (int m = 16; m >= 1; m >>= 1) mx = fmaxf(mx, __shfl_xor(mx, m));
                float ex = expf(lnap - mx);
                float sm = ex;
                #pragma unroll
                for (int m = 16; m >= 1; m >>= 1) sm += __shfl_xor(sm, m);
                *dp = (ex / sm) * a_s[g*16 + isub];  // r * a, in place (own element only)
            }
        }
        __syncthreads();                             // (2) r ready

        // ---- phase C: T sums over all i ----
        float T0 = 0.f, T1 = 0.f, T2 = 0.f;
        auto csum3 = [&](int ibase, auto getpair){
            #pragma unroll
            for (int s = 0; s < 8; ++s){
                float v0, v1; getpair(s, v0, v1);
                float r0 = dall[(ibase + 2*s)*34 + Bc];
                float r1 = dall[(ibase + 2*s + 1)*34 + Bc];
                T0 += r0 + r1;
                T1 += r0*v0 + r1*v1;
                T2 += r0*v0*v0 + r1*v1*v1;
            }
        };
        #pragma unroll
        for (int g = 0; g < 7; ++g)
            csum3(g*16, [&](int s, float& v0, float& v1){
                union { uint u; half2v h; } cv; cv.u = v_lds[g*8 + s][t];
                v0 = (float)cv.h.x; v1 = (float)cv.h.y; });
        #pragma unroll
        for (int c2 = 0; c2 < 11; ++c2)
            csum3((7+c2)*16, [&](int s, float& v0, float& v1){
                half2v vh = v_h[c2*8 + s];
                v0 = (float)vh.x; v1 = (float)vh.y; });

        // m-step
        const float inv = 1.f/(T0 + 1e-12f);
        const float mu  = T1 * inv;
        const float sg  = fmaxf((T2 - 2.f*mu*T1 + mu*mu*T0) * inv, 0.f) + 1e-12f;
        const float lg  = logf(sg);
        float cs = (bu + 0.5f*lg) * T0;
        float ls = lg + LOG_LN2PI;
        #pragma unroll
        for (int m = 1; m < 16; m <<= 1){ cs += __shfl_xor(cs, m, 16); ls += __shfl_xor(ls, m, 16); }
        const float aout = san(1.f/(1.f + expf(-lam*(ba - cs))), 1e-30f, 1.f);
        if (it == 0){
            mu_r = mu; i2s_r = 0.5f/sg;
            if (p == 0) cst[Bc] = logf(aout) - 0.5f*ls;
            __syncthreads();                         // (3) cst visible; dall reuse safe
        } else { muF = mu; aF = aout; }
    }

    // ---- outputs (fp32): [a_fin 4*32*49][pose_out 4*512*49] ----
    if (p == 0) out[bs*(B_*L_) + Bc*L_ + l] = san(aF, 0.f, 1.f);
    out[6272 + (bs*512 + t)*L_ + l] = san(muF, -1e4f, 1e4f);
}

// ================= launch =================
extern "C" void kernel_launch(void* const* d_in, const int* in_sizes, int n_in,
                              void* d_out, int out_size, void* d_ws, size_t ws_size,
                              hipStream_t stream)
{
    const float* a_in   = (const float*)d_in[0];
    const float* pose   = (const float*)d_in[1];
    const float* mpw    = (const float*)d_in[2];
    const float* mpb    = (const float*)d_in[3];
    const float* fw     = (const float*)d_in[4];
    // d_in[5..8] (ln_g, ln_b, spat_w, spat_bias) are provably dead: softmax over B of a
    // B-independent gate is exactly 1/B regardless of their values.
    const float* beta_u = (const float*)d_in[9];
    const float* beta_a = (const float*)d_in[10];
    float* out = (float*)d_out;

    // ---- ws layout (byte offsets) ----
    // csum [16] f32         @ 0      (64 B)
    // cpr  4x[16][592] u16  @ 256    (75776 B)
    // Xt   [3136][288] bf16 @ 76288  (1806336 B)   -> total 1.88 MB
    char* base = (char*)d_ws;
    float*  csum = (float*)(base + 0);
    ushort* cpr  = (ushort*)(base + 256);
    __hip_bfloat16* Xt = (__hip_bfloat16*)(base + 76288);

    const int nc = 18;
    const int nx = (NCOLS*KKA_ + 255)/256;   // 3528
    k_prep<<<nc + nx, 256, 0, stream>>>(fw, pose, cpr, csum, Xt, nc);
    k_mega<<<NSITE, 512, 0, stream>>>(cpr, Xt, a_in, mpw, mpb, csum, beta_u, beta_a, out);
}

// Round 2
// 258.036 us; speedup vs baseline: 1.0080x; 1.0080x over previous
//
#include <hip/hip_runtime.h>
#include <hip/hip_bf16.h>
#include <math.h>

// ---------------- problem constants ----------------
#define A_    32
#define B_    32
#define PS    16
#define KK_   9
#define KKA_  288      // KK_*A_
#define OH_   7
#define L_    49
#define NB    4
#define NSITE 196      // NB*L_
#define NCOLS 3136     // NSITE*16

#define LAM1 5.0e-4f        // 0.01*(1-0.95^1)
#define LAM2 9.75e-4f       // 0.01*(1-0.95^2)
#define LAM3 1.42625e-3f    // 0.01*(1-0.95^3)
#define LOG_LN2PI 0.6086775903077413f  // log(log(2*pi))

typedef _Float16 half2v __attribute__((ext_vector_type(2)));
typedef short    short8 __attribute__((ext_vector_type(8)));   // 8 bf16 (4 VGPRs)
typedef float    floatx4 __attribute__((ext_vector_type(4)));

static __device__ __forceinline__ float san(float x, float lo, float hi){
    return fminf(fmaxf(x, lo), hi);
}

static __device__ __forceinline__ float dot2acc(half2v a, half2v b, float c){
#if __has_builtin(__builtin_amdgcn_fdot2)
    return __builtin_amdgcn_fdot2(a, b, c, false);
#else
    return c + (float)a.x*(float)b.x + (float)a.y*(float)b.y;
#endif
}

// ================= K1: fused prep (cpr tables + full Xt unfold) =================
__global__ void k_prep(const float* __restrict__ fw, const float* __restrict__ pose,
                       ushort* __restrict__ cpr, float* __restrict__ csum,
                       __hip_bfloat16* __restrict__ Xt, int nc)
{
    if ((int)blockIdx.x < nc){
        int id = (int)blockIdx.x*256 + threadIdx.x;
        if (id >= 16*288) return;
        int p = id / 288, m = id % 288;
        float acc = fw[(0*16 + p)*2 + 0];
        for (int k = 1; k <= 143; ++k){
            float re = fw[(k*16 + p)*2 + 0];
            float im = fw[(k*16 + p)*2 + 1];
            int km = (k*m) % 288;
            float ang = 0.021816615649929116f * (float)km;  // 2*pi/288
            float s, c; __sincosf(ang, &s, &c);
            acc += 2.0f*(re*c - im*s);
        }
        float re144 = fw[(144*16 + p)*2 + 0];
        acc += re144 * ((m & 1) ? -1.0f : 1.0f);
        float cv = acc * (1.0f/288.0f);
        if (m == 0) cv += 1.0f;                            // + identity (residual)
        cv = san(cv, -1e4f, 1e4f);

        __hip_bfloat16 hb = __float2bfloat16(cv);
        float hif = __bfloat162float(hb);
        __hip_bfloat16 lb = __float2bfloat16(cv - hif);
        ushort hi = *(ushort*)&hb, lo = *(ushort*)&lb;

        ushort* c0h = cpr + p*592;
        ushort* c1h = cpr + 16*592   + p*592;
        ushort* c0l = cpr + 16*592*2 + p*592;
        ushort* c1l = cpr + 16*592*3 + p*592;
        int x1 = 288 - m;
        c0h[x1] = hi;  c0l[x1] = lo;
        c1h[x1-1] = hi; c1l[x1-1] = lo;
        if (m >= 1){
            int x2 = 576 - m;
            c0h[x2] = hi;  c0l[x2] = lo;
            c1h[x2-1] = hi; c1l[x2-1] = lo;
        } else {
            c0h[0] = hi; c0l[0] = lo;
            csum[p] = san(1.0f + fw[(0*16 + p)*2 + 0], -1e4f, 1e4f);
        }
        return;
    }
    // ---- Xt unfold, vectorized: one thread writes 8 consecutive bf16 (16 B) ----
    int id = ((int)blockIdx.x - nc)*256 + threadIdx.x;
    if (id >= NCOLS*KKA_/8) return;
    int c = id / (KKA_/8), j8 = id % (KKA_/8);
    int j = j8*8;                         // 8 consecutive a within one kk (8 | 32)
    int n = c >> 4, q = c & 15;
    int bs = n / L_, l = n % L_, oy = l / OH_, ox = l % OH_;
    int kk = j >> 5, a0 = j & 31;
    int y = oy*2 - 1 + kk/3, x = ox*2 - 1 + kk%3;
    const bool inb = ((unsigned)y < 14u && (unsigned)x < 14u);
    const float* psrc = pose + (((long)bs*(A_*PS))*14 + y)*14 + x;
    union { ushort us[8]; uint4 u4; } res;
    #pragma unroll
    for (int u = 0; u < 8; ++u){
        float v = 0.f;
        if (inb) v = psrc[((a0+u)*PS + q)*196];
        __hip_bfloat16 hb = __float2bfloat16(san(v, -1e4f, 1e4f));
        res.us[u] = *(ushort*)&hb;
    }
    *(uint4*)&Xt[c*KKA_ + j] = res.u4;    // 16B-aligned: (c*288+j)*2, j%8==0
}

// ================= K2: MEGA — per-site MFMA GEMM + v + 3 fused EM iterations =================
// Latency-focused structure (196 blocks, 1/CU, 2 waves/SIMD):
//  - phase 1: double-buffered 'us' -> 1 barrier/chunk; Xt B-fragments hoisted into bf[9]
//    registers. k0i loop is FORCIBLY unrolled: bf[] must be statically indexed or the
//    compiler demotes it to scratch (round-1 post-mortem: 114 MB of spill traffic).
//  - EM iterations: batched phases. Phase A computes ALL 288 d(i) into dall[288][34]
//    (no internal barriers), phase B all 18 softmax groups in-place, phase C all T-sums.
//    3 barriers/iteration instead of 36.
//  - dall aliases the phase-1 us double-buffer region. v split: 56 pairs in LDS
//    (114688 B) + 88 pairs in registers. Total LDS 155136 B.
__launch_bounds__(512, 1)
__global__ void
k_mega(const ushort* __restrict__ cpr, const __hip_bfloat16* __restrict__ Xt,
       const float* __restrict__ a_in,
       const float* __restrict__ mpw, const float* __restrict__ mpb,
       const float* __restrict__ csum,
       const float* __restrict__ beta_u, const float* __restrict__ beta_a,
       float* __restrict__ out)
{
    const int nl = blockIdx.x;          // site
    const int t = threadIdx.x;          // 512
    const int Bc = t >> 4, p = t & 15;  // EM thread = (Bc, p)
    const int bs = nl / L_, l = nl % L_;

    __shared__ uint v_lds[56][512];                 // 114688 B: v pairs chunks 0..6
    __shared__ __align__(16) float scratch[9792];   // 39168 B: dall[288][34] | us dbuf 2x8448B
    __shared__ float a_s[KKA_];                     // 1152 B
    __shared__ float cst[32];                       // 128 B   => 155136 B total

    float* const dall = scratch;

    // unfold this site's activation row
    for (int j = t; j < KKA_; j += 512){
        int kk = j >> 5, a = j & 31;
        int oy = l / OH_, ox = l % OH_;
        int y = oy*2 - 1 + kk/3, x = ox*2 - 1 + kk%3;
        float v = 0.f;
        if ((unsigned)y < 14u && (unsigned)x < 14u)
            v = a_in[((bs*A_ + a)*14 + y)*14 + x];
        a_s[j] = san(v, 0.f, 1e4f);
    }
    // per-thread weight row as packed fp16
    half2v w_h[8];
    #pragma unroll
    for (int k = 0; k < 8; ++k){
        w_h[k].x = (_Float16)mpw[t*16 + 2*k];
        w_h[k].y = (_Float16)mpw[t*16 + 2*k + 1];
    }
    const float vb = mpb[t] * csum[p];  // bias pushed through the filter
    const float bu = beta_u[Bc];
    const float ba = beta_a[Bc];

    // ---- GEMM lane mapping: wave w handles p_g in {2w, 2w+1} ----
    const int w = t >> 6, lane = t & 63;
    const int mn = lane & 15, quad = lane >> 4;
    const int p0 = w*2;

    // hoist chunk-invariant Xt B-fragments into registers (was 18x re-load)
    short8 bf[9];
    {
        const __hip_bfloat16* xrow = Xt + (nl*16 + mn)*KKA_ + quad*8;
        #pragma unroll
        for (int k = 0; k < 9; ++k) bf[k] = *(const short8*)&xrow[k*32];
    }
    __syncthreads();                    // a_s ready

    // S0tot: 4 accumulators to shorten the dependent-add chain
    float s0a = 0.f, s0b = 0.f, s0c = 0.f, s0d = 0.f;
    for (int j = 0; j < KKA_; j += 4){
        s0a += a_s[j]; s0b += a_s[j+1]; s0c += a_s[j+2]; s0d += a_s[j+3];
    }
    const float S0tot = (s0a + s0b) + (s0c + s0d);

    float S1 = 0.f, S2 = 0.f;
    half2v v_h[88];

    auto do_chunk = [&](int ch, _Float16* usb){
        floatx4 accA = {0,0,0,0}, accB = {0,0,0,0};
        #pragma unroll                               // CRITICAL: bf[k0i] must be static
        for (int k0i = 0; k0i < 9; ++k0i){
            const int k0 = k0i*32;
            short8 bfrag = bf[k0i];
            #pragma unroll
            for (int pp = 0; pp < 2; ++pp){
                const int pg = p0 + pp;
                int o = 288 + k0 + quad*8 - (ch*16 + mn);
                int sel = o & 1, off = o - sel;
                const ushort* bh = cpr + (sel ? 16*592 : 0) + pg*592;
                const ushort* bl = cpr + 16*592*2 + (sel ? 16*592 : 0) + pg*592;
                short8 ah = *(const short8*)&bh[off];
                short8 al = *(const short8*)&bl[off];
                floatx4 acc = pp ? accB : accA;
                acc = __builtin_amdgcn_mfma_f32_16x16x32_bf16(ah, bfrag, acc, 0, 0, 0);
                acc = __builtin_amdgcn_mfma_f32_16x16x32_bf16(al, bfrag, acc, 0, 0, 0);
                if (pp) accB = acc; else accA = acc;
            }
        }
        #pragma unroll
        for (int r = 0; r < 4; ++r){
            usb[p0*264     + (quad*4 + r)*16 + mn] = (_Float16)accA[r];
            usb[(p0+1)*264 + (quad*4 + r)*16 + mn] = (_Float16)accB[r];
        }
    };

    auto vpair = [&](const _Float16* urow, int s, float& v0o, float& v1o){
        union { uint4 u4; half2v h2[4]; } A0, A1, B0, B1;
        A0.u4 = *(const uint4*)&urow[(2*s)*16];
        A1.u4 = *(const uint4*)&urow[(2*s)*16 + 8];
        B0.u4 = *(const uint4*)&urow[(2*s+1)*16];
        B1.u4 = *(const uint4*)&urow[(2*s+1)*16 + 8];
        float v0 = vb, v1 = vb;
        #pragma unroll
        for (int m = 0; m < 4; ++m){
            v0 = dot2acc(A0.h2[m], w_h[m],   v0);
            v0 = dot2acc(A1.h2[m], w_h[4+m], v0);
            v1 = dot2acc(B0.h2[m], w_h[m],   v1);
            v1 = dot2acc(B1.h2[m], w_h[4+m], v1);
        }
        v0o = v0; v1o = v1;
    };

    // ---- phase 1: 18 chunks, double-buffered us, ONE barrier per chunk ----
    // (writes of chunk ch+2 to buffer b happen after barrier(ch+1), which orders
    //  them after all reads of chunk ch from the same buffer)
    for (int ch = 0; ch < 7; ++ch){                 // v -> LDS
        _Float16* usb = ((_Float16*)scratch) + (ch & 1)*4224;
        do_chunk(ch, usb);
        __syncthreads();                            // us chunk ready
        const _Float16* urow = &usb[p*264];
        #pragma unroll
        for (int s = 0; s < 8; ++s){
            float v0, v1; vpair(urow, s, v0, v1);
            const int i0 = ch*16 + 2*s;
            const float a0 = a_s[i0], a1 = a_s[i0+1];
            S1 += a0*v0 + a1*v1;
            S2 += a0*v0*v0 + a1*v1*v1;
            union { half2v h; uint u; } cv;
            cv.h.x = (_Float16)v0; cv.h.y = (_Float16)v1;
            v_lds[ch*8 + s][t] = cv.u;
        }
    }
    #pragma unroll
    for (int c2 = 0; c2 < 11; ++c2){                // v -> regs (constant indices)
        const int ch = 7 + c2;
        _Float16* usb = ((_Float16*)scratch) + (ch & 1)*4224;
        do_chunk(ch, usb);
        __syncthreads();
        const _Float16* urow = &usb[p*264];
        #pragma unroll
        for (int s = 0; s < 8; ++s){
            float v0, v1; vpair(urow, s, v0, v1);
            const int i0 = ch*16 + 2*s;
            const float a0 = a_s[i0], a1 = a_s[i0+1];
            S1 += a0*v0 + a1*v1;
            S2 += a0*v0*v0 + a1*v1*v1;
            half2v vh; vh.x = (_Float16)v0; vh.y = (_Float16)v1;
            v_h[c2*8 + s] = vh;
        }
    }

    // iter-1 m-step (r = 1/32 exactly); mu/i2s live in registers
    float mu_r, i2s_r;
    {
        const float rs  = S0tot * (1.0f/32.0f);
        const float inv = 1.0f / (rs + 1e-12f);
        const float S1r = S1 * (1.0f/32.0f), S2r = S2 * (1.0f/32.0f);
        mu_r = S1r * inv;
        const float sg  = fmaxf((S2r - 2.f*mu_r*S1r + mu_r*mu_r*rs) * inv, 0.f) + 1e-12f;
        i2s_r = 0.5f / sg;
        const float lg  = logf(sg);
        float cs = (bu + 0.5f*lg) * rs;
        float ls = lg + LOG_LN2PI;
        #pragma unroll
        for (int m = 1; m < 16; m <<= 1){ cs += __shfl_xor(cs, m, 16); ls += __shfl_xor(ls, m, 16); }
        const float aout = san(1.f/(1.f + expf(-LAM1*(ba - cs))), 1e-30f, 1.f);
        if (p == 0) cst[Bc] = logf(aout) - 0.5f*ls;
    }
    __syncthreads();    // publish cst AND protect us-region reuse as dall

    // ---- iterations 2,3: batched phases, 3 barriers each (was 36) ----
    const int b0 = p & 1, b1 = (p>>1)&1, b2 = (p>>2)&1, b3 = (p>>3)&1;
    const int isub = t >> 5, Bce = t & 31;
    float muF = 0.f, aF = 0.f;
    for (int it = 0; it < 2; ++it){
        const float lam = it ? LAM3 : LAM2;

        // ---- phase A: all 288 d(i) -> dall[(i)*34 + Bc], no internal barriers ----
        auto dtree = [&](int ibase, auto getpair){
            float e1[8], e2[4], e3[2], dfin;
            #pragma unroll
            for (int s = 0; s < 8; ++s){
                float v0, v1; getpair(s, v0, v1);
                float d0 = v0 - mu_r, d1 = v1 - mu_r;
                float ea = d0*d0*i2s_r, eb = d1*d1*i2s_r;
                float aown  = b0 ? eb : ea;
                float asend = b0 ? ea : eb;
                e1[s] = aown + __shfl_xor(asend, 1);
            }
            #pragma unroll
            for (int s = 0; s < 4; ++s){
                float aown  = b1 ? e1[2*s+1] : e1[2*s];
                float asend = b1 ? e1[2*s]   : e1[2*s+1];
                e2[s] = aown + __shfl_xor(asend, 2);
            }
            #pragma unroll
            for (int s = 0; s < 2; ++s){
                float aown  = b2 ? e2[2*s+1] : e2[2*s];
                float asend = b2 ? e2[2*s]   : e2[2*s+1];
                e3[s] = aown + __shfl_xor(asend, 4);
            }
            {
                float aown  = b3 ? e3[1] : e3[0];
                float asend = b3 ? e3[0] : e3[1];
                dfin = aown + __shfl_xor(asend, 8);
            }
            dall[(ibase + p)*34 + Bc] = dfin;        // lane p holds d(i = ibase+p)
        };
        #pragma unroll
        for (int g = 0; g < 7; ++g)
            dtree(g*16, [&](int s, float& v0, float& v1){
                union { uint u; half2v h; } cv; cv.u = v_lds[g*8 + s][t];
                v0 = (float)cv.h.x; v1 = (float)cv.h.y; });
        #pragma unroll
        for (int c2 = 0; c2 < 11; ++c2)
            dtree((7+c2)*16, [&](int s, float& v0, float& v1){
                half2v vh = v_h[c2*8 + s];
                v0 = (float)vh.x; v1 = (float)vh.y; });
        __syncthreads();                             // (1) dall ready

        // ---- phase B: softmax over B for ALL i, in place; thread -> (isub, Bce) ----
        {
            const float cb = cst[Bce];
            #pragma unroll
            for (int g = 0; g < 18; ++g){
                float* dp = &dall[(g*16 + isub)*34 + Bce];
                float lnap = cb - *dp;
                float mx = lnap;
                #pragma unroll
                for (int m = 16; m >= 1; m >>= 1) mx = fmaxf(mx, __shfl_xor(mx, m));
                float ex = expf(lnap - mx);
                float sm = ex;
                #pragma unroll
                for (int m = 16; m >= 1; m >>= 1) sm += __shfl_xor(sm, m);
                *dp = (ex / sm) * a_s[g*16 + isub];  // r * a, in place (own element only)
            }
        }
        __syncthreads();                             // (2) r ready

        // ---- phase C: T sums over all i ----
        float T0 = 0.f, T1 = 0.f, T2 = 0.f;
        auto csum3 = [&](int ibase, auto getpair){
            #pragma unroll
            for (int s = 0; s < 8; ++s){
                float v0, v1; getpair(s, v0, v1);
                float r0 = dall[(ibase + 2*s)*34 + Bc];
                float r1 = dall[(ibase + 2*s + 1)*34 + Bc];
                T0 += r0 + r1;
                T1 += r0*v0 + r1*v1;
                T2 += r0*v0*v0 + r1*v1*v1;
            }
        };
        #pragma unroll
        for (int g = 0; g < 7; ++g)
            csum3(g*16, [&](int s, float& v0, float& v1){
                union { uint u; half2v h; } cv; cv.u = v_lds[g*8 + s][t];
                v0 = (float)cv.h.x; v1 = (float)cv.h.y; });
        #pragma unroll
        for (int c2 = 0; c2 < 11; ++c2)
            csum3((7+c2)*16, [&](int s, float& v0, float& v1){
                half2v vh = v_h[c2*8 + s];
                v0 = (float)vh.x; v1 = (float)vh.y; });

        // m-step
        const float inv = 1.f/(T0 + 1e-12f);
        const float mu  = T1 * inv;
        const float sg  = fmaxf((T2 - 2.f*mu*T1 + mu*mu*T0) * inv, 0.f) + 1e-12f;
        const float lg  = logf(sg);
        float cs = (bu + 0.5f*lg) * T0;
        float ls = lg + LOG_LN2PI;
        #pragma unroll
        for (int m = 1; m < 16; m <<= 1){ cs += __shfl_xor(cs, m, 16); ls += __shfl_xor(ls, m, 16); }
        const float aout = san(1.f/(1.f + expf(-lam*(ba - cs))), 1e-30f, 1.f);
        if (it == 0){
            mu_r = mu; i2s_r = 0.5f/sg;
            if (p == 0) cst[Bc] = logf(aout) - 0.5f*ls;
            __syncthreads();                         // (3) cst visible; dall reuse safe
        } else { muF = mu; aF = aout; }
    }

    // ---- outputs (fp32): [a_fin 4*32*49][pose_out 4*512*49] ----
    if (p == 0) out[bs*(B_*L_) + Bc*L_ + l] = san(aF, 0.f, 1.f);
    out[6272 + (bs*512 + t)*L_ + l] = san(muF, -1e4f, 1e4f);
}

// ================= launch =================
extern "C" void kernel_launch(void* const* d_in, const int* in_sizes, int n_in,
                              void* d_out, int out_size, void* d_ws, size_t ws_size,
                              hipStream_t stream)
{
    const float* a_in   = (const float*)d_in[0];
    const float* pose   = (const float*)d_in[1];
    const float* mpw    = (const float*)d_in[2];
    const float* mpb    = (const float*)d_in[3];
    const float* fw     = (const float*)d_in[4];
    // d_in[5..8] (ln_g, ln_b, spat_w, spat_bias) are provably dead: softmax over B of a
    // B-independent gate is exactly 1/B regardless of their values.
    const float* beta_u = (const float*)d_in[9];
    const float* beta_a = (const float*)d_in[10];
    float* out = (float*)d_out;

    // ---- ws layout (byte offsets) ----
    // csum [16] f32         @ 0      (64 B)
    // cpr  4x[16][592] u16  @ 256    (75776 B)
    // Xt   [3136][288] bf16 @ 76288  (1806336 B)   -> total 1.88 MB
    char* base = (char*)d_ws;
    float*  csum = (float*)(base + 0);
    ushort* cpr  = (ushort*)(base + 256);
    __hip_bfloat16* Xt = (__hip_bfloat16*)(base + 76288);

    const int nc = 18;
    const int nx = (NCOLS*KKA_/8 + 255)/256;   // 441
    k_prep<<<nc + nx, 256, 0, stream>>>(fw, pose, cpr, csum, Xt, nc);
    k_mega<<<NSITE, 512, 0, stream>>>(cpr, Xt, a_in, mpw, mpb, csum, beta_u, beta_a, out);
}

// Round 3
// 257.198 us; speedup vs baseline: 1.0113x; 1.0033x over previous
//
#include <hip/hip_runtime.h>
#include <hip/hip_bf16.h>
#include <math.h>

// ---------------- problem constants ----------------
#define A_    32
#define B_    32
#define PS    16
#define KK_   9
#define KKA_  288      // KK_*A_
#define OH_   7
#define L_    49
#define NB    4
#define NSITE 196      // NB*L_
#define NCOLS 3136     // NSITE*16

#define LAM1 5.0e-4f        // 0.01*(1-0.95^1)
#define LAM2 9.75e-4f       // 0.01*(1-0.95^2)
#define LAM3 1.42625e-3f    // 0.01*(1-0.95^3)
#define LOG_LN2PI 0.6086775903077413f  // log(log(2*pi))

typedef _Float16 half2v __attribute__((ext_vector_type(2)));
typedef short    short8 __attribute__((ext_vector_type(8)));   // 8 bf16 (4 VGPRs)
typedef float    floatx4 __attribute__((ext_vector_type(4)));

static __device__ __forceinline__ float san(float x, float lo, float hi){
    return fminf(fmaxf(x, lo), hi);
}

static __device__ __forceinline__ float dot2acc(half2v a, half2v b, float c){
#if __has_builtin(__builtin_amdgcn_fdot2)
    return __builtin_amdgcn_fdot2(a, b, c, false);
#else
    return c + (float)a.x*(float)b.x + (float)a.y*(float)b.y;
#endif
}

// ================= K1: fused prep (cpr tables + full Xt unfold) =================
__global__ void k_prep(const float* __restrict__ fw, const float* __restrict__ pose,
                       ushort* __restrict__ cpr, float* __restrict__ csum,
                       __hip_bfloat16* __restrict__ Xt, int nc)
{
    if ((int)blockIdx.x < nc){
        int id = (int)blockIdx.x*256 + threadIdx.x;
        if (id >= 16*288) return;
        int p = id / 288, m = id % 288;
        float acc = fw[(0*16 + p)*2 + 0];
        for (int k = 1; k <= 143; ++k){
            float re = fw[(k*16 + p)*2 + 0];
            float im = fw[(k*16 + p)*2 + 1];
            int km = (k*m) % 288;
            float ang = 0.021816615649929116f * (float)km;  // 2*pi/288
            float s, c; __sincosf(ang, &s, &c);
            acc += 2.0f*(re*c - im*s);
        }
        float re144 = fw[(144*16 + p)*2 + 0];
        acc += re144 * ((m & 1) ? -1.0f : 1.0f);
        float cv = acc * (1.0f/288.0f);
        if (m == 0) cv += 1.0f;                            // + identity (residual)
        cv = san(cv, -1e4f, 1e4f);

        __hip_bfloat16 hb = __float2bfloat16(cv);
        float hif = __bfloat162float(hb);
        __hip_bfloat16 lb = __float2bfloat16(cv - hif);
        ushort hi = *(ushort*)&hb, lo = *(ushort*)&lb;

        ushort* c0h = cpr + p*592;
        ushort* c1h = cpr + 16*592   + p*592;
        ushort* c0l = cpr + 16*592*2 + p*592;
        ushort* c1l = cpr + 16*592*3 + p*592;
        int x1 = 288 - m;
        c0h[x1] = hi;  c0l[x1] = lo;
        c1h[x1-1] = hi; c1l[x1-1] = lo;
        if (m >= 1){
            int x2 = 576 - m;
            c0h[x2] = hi;  c0l[x2] = lo;
            c1h[x2-1] = hi; c1l[x2-1] = lo;
        } else {
            c0h[0] = hi; c0l[0] = lo;
            csum[p] = san(1.0f + fw[(0*16 + p)*2 + 0], -1e4f, 1e4f);
        }
        return;
    }
    // ---- Xt unfold, vectorized: one thread writes 8 consecutive bf16 (16 B) ----
    int id = ((int)blockIdx.x - nc)*256 + threadIdx.x;
    if (id >= NCOLS*KKA_/8) return;
    int c = id / (KKA_/8), j8 = id % (KKA_/8);
    int j = j8*8;                         // 8 consecutive a within one kk (8 | 32)
    int n = c >> 4, q = c & 15;
    int bs = n / L_, l = n % L_, oy = l / OH_, ox = l % OH_;
    int kk = j >> 5, a0 = j & 31;
    int y = oy*2 - 1 + kk/3, x = ox*2 - 1 + kk%3;
    const bool inb = ((unsigned)y < 14u && (unsigned)x < 14u);
    const float* psrc = pose + (((long)bs*(A_*PS))*14 + y)*14 + x;
    union { ushort us[8]; uint4 u4; } res;
    #pragma unroll
    for (int u = 0; u < 8; ++u){
        float v = 0.f;
        if (inb) v = psrc[((a0+u)*PS + q)*196];
        __hip_bfloat16 hb = __float2bfloat16(san(v, -1e4f, 1e4f));
        res.us[u] = *(ushort*)&hb;
    }
    *(uint4*)&Xt[c*KKA_ + j] = res.u4;    // 16B-aligned: (c*288+j)*2, j%8==0
}

// ================= K2: MEGA — per-site MFMA GEMM + v + 3 fused EM iterations =================
// Register-pressure discipline (round-2 post-mortem: allocator caps at 128 VGPRs and
// spills ~45 regs -> 114 MB scratch traffic):
//  - NO bf[] hoist (xrow loads are L1-resident after chunk 0)      (-36 regs)
//  - v split: 48 pairs LDS + 80 pairs regs + 16 pairs RECOMPUTED from U retained in
//    the us double-buffer (chunks 16,17 are the last writers of buf0/buf1). (-8 regs)
//  - dall has its own LDS array (no aliasing with us needed anymore).
//  - amdgpu_waves_per_eu(1,2): occupancy is structurally 2 waves/SIMD (LDS-limited
//    1 block/CU), so give the allocator the true budget (256/wave).
// Demand estimate: 80 (v_h) + 44 (round-0 measured misc) = 124 <= 128 even if the
// attribute is ignored.
__global__ __attribute__((amdgpu_flat_work_group_size(512,512), amdgpu_waves_per_eu(1,2)))
void
k_mega(const ushort* __restrict__ cpr, const __hip_bfloat16* __restrict__ Xt,
       const float* __restrict__ a_in,
       const float* __restrict__ mpw, const float* __restrict__ mpb,
       const float* __restrict__ csum,
       const float* __restrict__ beta_u, const float* __restrict__ beta_a,
       float* __restrict__ out)
{
    const int nl = blockIdx.x;          // site
    const int t = threadIdx.x;          // 512
    const int Bc = t >> 4, p = t & 15;  // EM thread = (Bc, p)
    const int bs = nl / L_, l = nl % L_;

    __shared__ uint v_lds[48][512];                 //  98304 B: v pairs chunks 0..5
    __shared__ __align__(16) _Float16 us[2*4224];   //  16896 B: GEMM dbuf; chunks 16,17 retained
    __shared__ float dall[288*34];                  //  39168 B: d / r, stride 34
    __shared__ float a_s[KKA_];                     //   1152 B
    __shared__ float cst[32];                       //    128 B   => 155648 B total

    // unfold this site's activation row
    for (int j = t; j < KKA_; j += 512){
        int kk = j >> 5, a = j & 31;
        int oy = l / OH_, ox = l % OH_;
        int y = oy*2 - 1 + kk/3, x = ox*2 - 1 + kk%3;
        float v = 0.f;
        if ((unsigned)y < 14u && (unsigned)x < 14u)
            v = a_in[((bs*A_ + a)*14 + y)*14 + x];
        a_s[j] = san(v, 0.f, 1e4f);
    }
    // per-thread weight row as packed fp16
    half2v w_h[8];
    #pragma unroll
    for (int k = 0; k < 8; ++k){
        w_h[k].x = (_Float16)mpw[t*16 + 2*k];
        w_h[k].y = (_Float16)mpw[t*16 + 2*k + 1];
    }
    const float vb = mpb[t] * csum[p];  // bias pushed through the filter
    const float bu = beta_u[Bc];
    const float ba = beta_a[Bc];
    __syncthreads();                    // a_s ready

    // S0tot: 4 accumulators to shorten the dependent-add chain
    float s0a = 0.f, s0b = 0.f, s0c = 0.f, s0d = 0.f;
    for (int j = 0; j < KKA_; j += 4){
        s0a += a_s[j]; s0b += a_s[j+1]; s0c += a_s[j+2]; s0d += a_s[j+3];
    }
    const float S0tot = (s0a + s0b) + (s0c + s0d);

    // ---- GEMM lane mapping: wave w handles p_g in {2w, 2w+1} ----
    const int w = t >> 6, lane = t & 63;
    const int mn = lane & 15, quad = lane >> 4;
    const int p0 = w*2;
    const __hip_bfloat16* xrow = Xt + (nl*16 + mn)*KKA_ + quad*8;

    float S1 = 0.f, S2 = 0.f;
    half2v v_h[80];

    auto do_chunk = [&](int ch, _Float16* usb){
        floatx4 accA = {0,0,0,0}, accB = {0,0,0,0};
        for (int k0i = 0; k0i < 9; ++k0i){
            const int k0 = k0i*32;
            short8 bfrag = *(const short8*)&xrow[k0];
            #pragma unroll
            for (int pp = 0; pp < 2; ++pp){
                const int pg = p0 + pp;
                int o = 288 + k0 + quad*8 - (ch*16 + mn);
                int sel = o & 1, off = o - sel;
                const ushort* bh = cpr + (sel ? 16*592 : 0) + pg*592;
                const ushort* bl = cpr + 16*592*2 + (sel ? 16*592 : 0) + pg*592;
                short8 ah = *(const short8*)&bh[off];
                short8 al = *(const short8*)&bl[off];
                floatx4 acc = pp ? accB : accA;
                acc = __builtin_amdgcn_mfma_f32_16x16x32_bf16(ah, bfrag, acc, 0, 0, 0);
                acc = __builtin_amdgcn_mfma_f32_16x16x32_bf16(al, bfrag, acc, 0, 0, 0);
                if (pp) accB = acc; else accA = acc;
            }
        }
        #pragma unroll
        for (int r = 0; r < 4; ++r){
            usb[p0*264     + (quad*4 + r)*16 + mn] = (_Float16)accA[r];
            usb[(p0+1)*264 + (quad*4 + r)*16 + mn] = (_Float16)accB[r];
        }
    };

    auto vpair = [&](const _Float16* urow, int s, float& v0o, float& v1o){
        union { uint4 u4; half2v h2[4]; } A0, A1, B0, B1;
        A0.u4 = *(const uint4*)&urow[(2*s)*16];
        A1.u4 = *(const uint4*)&urow[(2*s)*16 + 8];
        B0.u4 = *(const uint4*)&urow[(2*s+1)*16];
        B1.u4 = *(const uint4*)&urow[(2*s+1)*16 + 8];
        float v0 = vb, v1 = vb;
        #pragma unroll
        for (int m = 0; m < 4; ++m){
            v0 = dot2acc(A0.h2[m], w_h[m],   v0);
            v0 = dot2acc(A1.h2[m], w_h[4+m], v0);
            v1 = dot2acc(B0.h2[m], w_h[m],   v1);
            v1 = dot2acc(B1.h2[m], w_h[4+m], v1);
        }
        v0o = v0; v1o = v1;
    };

    // ---- phase 1: 18 chunks, double-buffered us, ONE barrier per chunk ----
    // (writes of chunk ch+2 to buffer b happen after barrier(ch+1), which orders
    //  them after all reads of chunk ch from the same buffer)
    for (int ch = 0; ch < 6; ++ch){                 // chunks 0..5: v -> LDS
        _Float16* usb = us + (ch & 1)*4224;
        do_chunk(ch, usb);
        __syncthreads();                            // us chunk ready
        const _Float16* urow = &usb[p*264];
        #pragma unroll
        for (int s = 0; s < 8; ++s){
            float v0, v1; vpair(urow, s, v0, v1);
            const int i0 = ch*16 + 2*s;
            const float a0 = a_s[i0], a1 = a_s[i0+1];
            S1 += a0*v0 + a1*v1;
            S2 += a0*v0*v0 + a1*v1*v1;
            union { half2v h; uint u; } cv;
            cv.h.x = (_Float16)v0; cv.h.y = (_Float16)v1;
            v_lds[ch*8 + s][t] = cv.u;
        }
    }
    #pragma unroll
    for (int c2 = 0; c2 < 10; ++c2){                // chunks 6..15: v -> regs
        const int ch = 6 + c2;
        _Float16* usb = us + (ch & 1)*4224;
        do_chunk(ch, usb);
        __syncthreads();
        const _Float16* urow = &usb[p*264];
        #pragma unroll
        for (int s = 0; s < 8; ++s){
            float v0, v1; vpair(urow, s, v0, v1);
            const int i0 = ch*16 + 2*s;
            const float a0 = a_s[i0], a1 = a_s[i0+1];
            S1 += a0*v0 + a1*v1;
            S2 += a0*v0*v0 + a1*v1*v1;
            half2v vh; vh.x = (_Float16)v0; vh.y = (_Float16)v1;
            v_h[c2*8 + s] = vh;
        }
    }
    #pragma unroll
    for (int ch = 16; ch < 18; ++ch){               // chunks 16,17: U RETAINED in us
        _Float16* usb = us + (ch & 1)*4224;
        do_chunk(ch, usb);
        __syncthreads();
        const _Float16* urow = &usb[p*264];
        #pragma unroll
        for (int s = 0; s < 8; ++s){
            float v0, v1; vpair(urow, s, v0, v1);
            const int i0 = ch*16 + 2*s;
            const float a0 = a_s[i0], a1 = a_s[i0+1];
            S1 += a0*v0 + a1*v1;
            S2 += a0*v0*v0 + a1*v1*v1;
        }
    }
    // NOTE: us (chunks 16,17) must stay intact through the EM iterations.

    // iter-1 m-step (r = 1/32 exactly); mu/i2s live in registers
    float mu_r, i2s_r;
    {
        const float rs  = S0tot * (1.0f/32.0f);
        const float inv = 1.0f / (rs + 1e-12f);
        const float S1r = S1 * (1.0f/32.0f), S2r = S2 * (1.0f/32.0f);
        mu_r = S1r * inv;
        const float sg  = fmaxf((S2r - 2.f*mu_r*S1r + mu_r*mu_r*rs) * inv, 0.f) + 1e-12f;
        i2s_r = 0.5f / sg;
        const float lg  = logf(sg);
        float cs = (bu + 0.5f*lg) * rs;
        float ls = lg + LOG_LN2PI;
        #pragma unroll
        for (int m = 1; m < 16; m <<= 1){ cs += __shfl_xor(cs, m, 16); ls += __shfl_xor(ls, m, 16); }
        const float aout = san(1.f/(1.f + expf(-LAM1*(ba - cs))), 1e-30f, 1.f);
        if (p == 0) cst[Bc] = logf(aout) - 0.5f*ls;
    }
    __syncthreads();    // publish cst

    // ---- iterations 2,3: batched phases, 3 barriers each ----
    const int b0 = p & 1, b1 = (p>>1)&1, b2 = (p>>2)&1, b3 = (p>>3)&1;
    const int isub = t >> 5, Bce = t & 31;
    float muF = 0.f, aF = 0.f;
    for (int it = 0; it < 2; ++it){
        const float lam = it ? LAM3 : LAM2;

        // ---- phase A: all 288 d(i) -> dall[i*34 + Bc], no internal barriers ----
        auto dtree = [&](int ibase, auto getpair){
            float e1[8], e2[4], e3[2], dfin;
            #pragma unroll
            for (int s = 0; s < 8; ++s){
                float v0, v1; getpair(s, v0, v1);
                float d0 = v0 - mu_r, d1 = v1 - mu_r;
                float ea = d0*d0*i2s_r, eb = d1*d1*i2s_r;
                float aown  = b0 ? eb : ea;
                float asend = b0 ? ea : eb;
                e1[s] = aown + __shfl_xor(asend, 1);
            }
            #pragma unroll
            for (int s = 0; s < 4; ++s){
                float aown  = b1 ? e1[2*s+1] : e1[2*s];
                float asend = b1 ? e1[2*s]   : e1[2*s+1];
                e2[s] = aown + __shfl_xor(asend, 2);
            }
            #pragma unroll
            for (int s = 0; s < 2; ++s){
                float aown  = b2 ? e2[2*s+1] : e2[2*s];
                float asend = b2 ? e2[2*s]   : e2[2*s+1];
                e3[s] = aown + __shfl_xor(asend, 4);
            }
            {
                float aown  = b3 ? e3[1] : e3[0];
                float asend = b3 ? e3[0] : e3[1];
                dfin = aown + __shfl_xor(asend, 8);
            }
            dall[(ibase + p)*34 + Bc] = dfin;        // lane p holds d(i = ibase+p)
        };
        for (int g = 0; g < 6; ++g)
            dtree(g*16, [&](int s, float& v0, float& v1){
                union { uint u; half2v h; } cv; cv.u = v_lds[g*8 + s][t];
                v0 = (float)cv.h.x; v1 = (float)cv.h.y; });
        #pragma unroll
        for (int c2 = 0; c2 < 10; ++c2)
            dtree((6+c2)*16, [&](int s, float& v0, float& v1){
                half2v vh = v_h[c2*8 + s];
                v0 = (float)vh.x; v1 = (float)vh.y; });
        #pragma unroll
        for (int ch = 16; ch < 18; ++ch){
            const _Float16* urow = &us[(ch & 1)*4224 + p*264];
            dtree(ch*16, [&](int s, float& v0, float& v1){
                vpair(urow, s, v0, v1); });
        }
        __syncthreads();                             // (1) dall ready

        // ---- phase B: softmax over B for ALL i, in place; thread -> (isub, Bce) ----
        {
            const float cb = cst[Bce];
            #pragma unroll
            for (int g = 0; g < 18; ++g){
                float* dp = &dall[(g*16 + isub)*34 + Bce];
                float lnap = cb - *dp;
                float mx = lnap;
                #pragma unroll
                for (int m = 16; m >= 1; m >>= 1) mx = fmaxf(mx, __shfl_xor(mx, m));
                float ex = expf(lnap - mx);
                float sm = ex;
                #pragma unroll
                for (int m = 16; m >= 1; m >>= 1) sm += __shfl_xor(sm, m);
                *dp = (ex / sm) * a_s[g*16 + isub];  // r * a, in place (own element only)
            }
        }
        __syncthreads();                             // (2) r ready

        // ---- phase C: T sums over all i ----
        float T0 = 0.f, T1 = 0.f, T2 = 0.f;
        auto csum3 = [&](int ibase, auto getpair){
            #pragma unroll
            for (int s = 0; s < 8; ++s){
                float v0, v1; getpair(s, v0, v1);
                float r0 = dall[(ibase + 2*s)*34 + Bc];
                float r1 = dall[(ibase + 2*s + 1)*34 + Bc];
                T0 += r0 + r1;
                T1 += r0*v0 + r1*v1;
                T2 += r0*v0*v0 + r1*v1*v1;
            }
        };
        for (int g = 0; g < 6; ++g)
            csum3(g*16, [&](int s, float& v0, float& v1){
                union { uint u; half2v h; } cv; cv.u = v_lds[g*8 + s][t];
                v0 = (float)cv.h.x; v1 = (float)cv.h.y; });
        #pragma unroll
        for (int c2 = 0; c2 < 10; ++c2)
            csum3((6+c2)*16, [&](int s, float& v0, float& v1){
                half2v vh = v_h[c2*8 + s];
                v0 = (float)vh.x; v1 = (float)vh.y; });
        #pragma unroll
        for (int ch = 16; ch < 18; ++ch){
            const _Float16* urow = &us[(ch & 1)*4224 + p*264];
            csum3(ch*16, [&](int s, float& v0, float& v1){
                vpair(urow, s, v0, v1); });
        }

        // m-step
        const float inv = 1.f/(T0 + 1e-12f);
        const float mu  = T1 * inv;
        const float sg  = fmaxf((T2 - 2.f*mu*T1 + mu*mu*T0) * inv, 0.f) + 1e-12f;
        const float lg  = logf(sg);
        float cs = (bu + 0.5f*lg) * T0;
        float ls = lg + LOG_LN2PI;
        #pragma unroll
        for (int m = 1; m < 16; m <<= 1){ cs += __shfl_xor(cs, m, 16); ls += __shfl_xor(ls, m, 16); }
        const float aout = san(1.f/(1.f + expf(-lam*(ba - cs))), 1e-30f, 1.f);
        if (it == 0){
            mu_r = mu; i2s_r = 0.5f/sg;
            if (p == 0) cst[Bc] = logf(aout) - 0.5f*ls;
            __syncthreads();                         // (3) cst visible; dall reuse safe
        } else { muF = mu; aF = aout; }
    }

    // ---- outputs (fp32): [a_fin 4*32*49][pose_out 4*512*49] ----
    if (p == 0) out[bs*(B_*L_) + Bc*L_ + l] = san(aF, 0.f, 1.f);
    out[6272 + (bs*512 + t)*L_ + l] = san(muF, -1e4f, 1e4f);
}

// ================= launch =================
extern "C" void kernel_launch(void* const* d_in, const int* in_sizes, int n_in,
                              void* d_out, int out_size, void* d_ws, size_t ws_size,
                              hipStream_t stream)
{
    const float* a_in   = (const float*)d_in[0];
    const float* pose   = (const float*)d_in[1];
    const float* mpw    = (const float*)d_in[2];
    const float* mpb    = (const float*)d_in[3];
    const float* fw     = (const float*)d_in[4];
    // d_in[5..8] (ln_g, ln_b, spat_w, spat_bias) are provably dead: softmax over B of a
    // B-independent gate is exactly 1/B regardless of their values.
    const float* beta_u = (const float*)d_in[9];
    const float* beta_a = (const float*)d_in[10];
    float* out = (float*)d_out;

    // ---- ws layout (byte offsets) ----
    // csum [16] f32         @ 0      (64 B)
    // cpr  4x[16][592] u16  @ 256    (75776 B)
    // Xt   [3136][288] bf16 @ 76288  (1806336 B)   -> total 1.88 MB
    char* base = (char*)d_ws;
    float*  csum = (float*)(base + 0);
    ushort* cpr  = (ushort*)(base + 256);
    __hip_bfloat16* Xt = (__hip_bfloat16*)(base + 76288);

    const int nc = 18;
    const int nx = (NCOLS*KKA_/8 + 255)/256;   // 441
    k_prep<<<nc + nx, 256, 0, stream>>>(fw, pose, cpr, csum, Xt, nc);
    k_mega<<<NSITE, 512, 0, stream>>>(cpr, Xt, a_in, mpw, mpb, csum, beta_u, beta_a, out);
}